// Round 4
// baseline (109.594 us; speedup 1.0000x reference)
//
#include <hip/hip_runtime.h>

typedef __attribute__((ext_vector_type(8))) short bf8_t;   // 8 x bf16 (4 VGPRs)
typedef __attribute__((ext_vector_type(4))) float f4_t;    // 4 x f32
typedef __attribute__((ext_vector_type(4))) int   i4_t;    // 16 B LDS write

static __device__ __forceinline__ short f2bf(float f) {
    union { float f; unsigned u; } v; v.f = f;
    unsigned r = v.u + 0x7fffu + ((v.u >> 16) & 1u);   // round-to-nearest-even
    return (short)(r >> 16);
}
static __device__ __forceinline__ float bf2f(short s) {
    union { unsigned u; float f; } v;
    v.u = ((unsigned)(unsigned short)s) << 16;
    return v.f;
}

// ---------------------------------------------------------------------------
// ONE kernel, ONE dispatch, ZERO inter-block synchronization.
// Block (b,ti,tj) computes out tile [128 i][128 j] by privately recomputing
// the two t-panels it needs (redundancy 16x = ~0.5us MFMA/block) into LDS.
// No workspace, no barrier, no flags -> eliminates all kernel-boundary and
// grid-sync costs that rounds 0-3 showed were insensitive to in-kernel tuning.
//
// Phase A (proven r2 math): t = P^T x x^T per 16-row tile. P staged per
// 256-K chunk into LDS ([64 m][256 k] bf16). Staging item = one m-row x 8 k
// -> one 16B slot: LDS writes are slot-balanced (optimal 8-cycle b128), reads
// use the r2-proven XOR swizzle (slot ^= m&7) -> conflict-free.
// 8 waves: waves 0-3 i-panel, 4-7 j-panel (diag blocks: j = copy of i, fully
// uniform code, deterministic -> identical t values everywhere).
// Phase B (proven r3 math): A=t_j, B=t_i; D col=nr->i, row=quad*4+r->j
// -> float4 stores. norms from ROUNDED bf16 (diagonal consistency).
// ---------------------------------------------------------------------------
__global__ void __launch_bounds__(512, 2)
fused_kernel(const float* __restrict__ x, const float* __restrict__ P,
             float* __restrict__ out)
{
    const int tid  = threadIdx.x;
    const int w    = tid >> 6;          // wave 0..7
    const int lane = tid & 63;
    const int nr   = lane & 15;
    const int quad = lane >> 4;

    // XCD chunk swizzle (bijective, 256 % 8 == 0): 32 consecutive tiles/XCD,
    // consecutive tiles share ti -> i-panel of x stays hot in that XCD's L2.
    const int swz = (blockIdx.x & 7) * 32 + (blockIdx.x >> 3);
    const int b   = swz >> 6;
    const int ti  = (swz >> 3) & 7;
    const int tj  = swz & 7;

    __shared__ __align__(16) char  p_lds[32768];        // P^T chunk [64 m][256 k] bf16
    __shared__ __align__(16) short t_lds[2][128][64];   // bf16 t panels (XOR-swizzled rows)
    __shared__ float nrm_lds[2][128];

    // ---------------- phase A: private t panels ----------------
    const int pan     = w >> 2;                 // 0 = i-panel, 1 = j-panel
    const int wl      = w & 3;                  // wave-in-panel: rows wl*32..+31
    const int panbase = (pan ? tj : ti) * 128;

    const float* xr0 = x + (size_t)(b * 1024 + panbase + wl * 32 + nr) * 1024;
    const float* xr1 = xr0 + (size_t)16 * 1024;

    f4_t acc[2][4];
    #pragma unroll
    for (int tt = 0; tt < 2; tt++)
        #pragma unroll
        for (int mt = 0; mt < 4; mt++) acc[tt][mt] = f4_t{0.f, 0.f, 0.f, 0.f};

    for (int c = 0; c < 4; ++c) {               // K chunks of 256
        // x prefetch: both row-tiles, whole chunk (32 dwordx4 in flight/lane)
        f4_t xv0[8][2], xv1[8][2];
        #pragma unroll
        for (int kt = 0; kt < 8; ++kt) {
            const int kb = c * 256 + kt * 32 + quad * 8;
            xv0[kt][0] = *(const f4_t*)(xr0 + kb);
            xv0[kt][1] = *(const f4_t*)(xr0 + kb + 4);
            xv1[kt][0] = *(const f4_t*)(xr1 + kb);
            xv1[kt][1] = *(const f4_t*)(xr1 + kb + 4);
        }
        // stage P chunk -> LDS (item: m-row x 8 k -> one 16B slot, slot ^= m&7)
        #pragma unroll
        for (int it = 0; it < 4; ++it) {
            const int idx = it * 512 + tid;     // 0..2047
            const int m   = idx & 63;
            const int ks  = idx >> 6;           // 16B slot 0..31
            const float* ps = P + (size_t)(c * 256 + ks * 8) * 64 + m;
            int d0, d1, d2, d3;
            d0 = ((int)(unsigned short)f2bf(ps[1 * 64]) << 16) | (unsigned short)f2bf(ps[0 * 64]);
            d1 = ((int)(unsigned short)f2bf(ps[3 * 64]) << 16) | (unsigned short)f2bf(ps[2 * 64]);
            d2 = ((int)(unsigned short)f2bf(ps[5 * 64]) << 16) | (unsigned short)f2bf(ps[4 * 64]);
            d3 = ((int)(unsigned short)f2bf(ps[7 * 64]) << 16) | (unsigned short)f2bf(ps[6 * 64]);
            *(i4_t*)(p_lds + m * 512 + ((ks * 16) ^ ((m & 7) << 4))) = i4_t{d0, d1, d2, d3};
        }
        __syncthreads();                        // stage complete
        #pragma unroll
        for (int kt = 0; kt < 8; ++kt) {
            const int colb = (kt * 64 + quad * 16) ^ ((nr & 7) << 4);
            bf8_t afr[4];
            #pragma unroll
            for (int mt = 0; mt < 4; ++mt)
                afr[mt] = *(const bf8_t*)(p_lds + (mt * 16 + nr) * 512 + colb);
            bf8_t b0, b1;
            #pragma unroll
            for (int j = 0; j < 4; ++j) {
                b0[j] = f2bf(xv0[kt][0][j]); b0[4 + j] = f2bf(xv0[kt][1][j]);
                b1[j] = f2bf(xv1[kt][0][j]); b1[4 + j] = f2bf(xv1[kt][1][j]);
            }
            #pragma unroll
            for (int mt = 0; mt < 4; ++mt)
                acc[0][mt] = __builtin_amdgcn_mfma_f32_16x16x32_bf16(afr[mt], b0, acc[0][mt], 0, 0, 0);
            #pragma unroll
            for (int mt = 0; mt < 4; ++mt)
                acc[1][mt] = __builtin_amdgcn_mfma_f32_16x16x32_bf16(afr[mt], b1, acc[1][mt], 0, 0, 0);
        }
        __syncthreads();                        // all reads done before restage
    }

    // epilogue: round to bf16, write t_lds (swizzled) + norms from ROUNDED
    #pragma unroll
    for (int tt = 0; tt < 2; ++tt) {
        const int srow = wl * 32 + tt * 16 + nr;        // 0..127 within panel
        char* trow = (char*)t_lds[pan] + srow * 128;
        float nrm = 0.f;
        #pragma unroll
        for (int mt = 0; mt < 4; ++mt) {
            const short s0 = f2bf(acc[tt][mt][0]), s1 = f2bf(acc[tt][mt][1]);
            const short s2 = f2bf(acc[tt][mt][2]), s3 = f2bf(acc[tt][mt][3]);
            const float b0 = bf2f(s0), b1 = bf2f(s1), b2 = bf2f(s2), b3 = bf2f(s3);
            nrm += b0 * b0 + b1 * b1 + b2 * b2 + b3 * b3;
            uint2 pk;
            pk.x = ((unsigned)(unsigned short)s1 << 16) | (unsigned short)s0;
            pk.y = ((unsigned)(unsigned short)s3 << 16) | (unsigned short)s2;
            // m = mt*16 + quad*4 + {0..3} -> byte mt*32 + quad*8, swizzled
            *(uint2*)(trow + ((mt * 32 + quad * 8) ^ ((srow & 7) << 4))) = pk;
        }
        nrm += __shfl_xor(nrm, 16);
        nrm += __shfl_xor(nrm, 32);
        if (quad == 0) nrm_lds[pan][srow] = nrm;
    }
    __syncthreads();

    // ---------------- phase B: pairwise 128x128 from LDS ----------------
    const int wy = w >> 2;                      // i half (64 rows)
    const int wx = w & 3;                       // j quarter (32 cols)
    const int i0 = wy * 64, j0 = wx * 32;

    f4_t pac[4][2];
    #pragma unroll
    for (int ia = 0; ia < 4; ia++)
        #pragma unroll
        for (int jb = 0; jb < 2; jb++) pac[ia][jb] = f4_t{0.f, 0.f, 0.f, 0.f};

    #pragma unroll
    for (int kt = 0; kt < 2; ++kt) {
        const int colb = kt * 64 + quad * 16;   // rank bytes
        bf8_t A[2], Bv[4];
        #pragma unroll
        for (int jb = 0; jb < 2; ++jb) {
            const int row = j0 + jb * 16 + nr;
            A[jb] = *(const bf8_t*)((char*)t_lds[1] + row * 128 + (colb ^ ((row & 7) << 4)));
        }
        #pragma unroll
        for (int ia = 0; ia < 4; ++ia) {
            const int row = i0 + ia * 16 + nr;
            Bv[ia] = *(const bf8_t*)((char*)t_lds[0] + row * 128 + (colb ^ ((row & 7) << 4)));
        }
        #pragma unroll
        for (int ia = 0; ia < 4; ++ia)
            #pragma unroll
            for (int jb = 0; jb < 2; ++jb)
                pac[ia][jb] = __builtin_amdgcn_mfma_f32_16x16x32_bf16(A[jb], Bv[ia], pac[ia][jb], 0, 0, 0);
    }

    // out = n_i + n_j - 2*G ; D col = nr -> i, row = quad*4+r -> j (float4)
    #pragma unroll
    for (int ia = 0; ia < 4; ++ia) {
        const int il  = i0 + ia * 16 + nr;
        const float niv = nrm_lds[0][il];
        float* orow = out + ((size_t)(b * 1024 + ti * 128 + il)) * 1024 + tj * 128;
        #pragma unroll
        for (int jb = 0; jb < 2; ++jb) {
            const int jo = j0 + jb * 16 + quad * 4;
            const float4 nv = *(const float4*)&nrm_lds[1][jo];   // 16B aligned
            f4_t a = pac[ia][jb];
            float4 v;
            v.x = niv + nv.x - 2.f * a[0];
            v.y = niv + nv.y - 2.f * a[1];
            v.z = niv + nv.z - 2.f * a[2];
            v.w = niv + nv.w - 2.f * a[3];
            *(float4*)(orow + jo) = v;
        }
    }
}

// ---------------------------------------------------------------------------
extern "C" void kernel_launch(void* const* d_in, const int* in_sizes, int n_in,
                              void* d_out, int out_size, void* d_ws, size_t ws_size,
                              hipStream_t stream) {
    const float* x = (const float*)d_in[0];   // [4,1024,1024] fp32
    const float* P = (const float*)d_in[1];   // [1024,64]     fp32
    float* out = (float*)d_out;               // [4,1024,1024] fp32
    (void)d_ws; (void)ws_size;                // no workspace, no memset, 1 dispatch

    fused_kernel<<<256, 512, 0, stream>>>(x, P, out);
}

// Round 5
// 107.361 us; speedup vs baseline: 1.0208x; 1.0208x over previous
//
#include <hip/hip_runtime.h>

typedef __attribute__((ext_vector_type(8))) short bf8_t;   // 8 x bf16 (4 VGPRs)
typedef __attribute__((ext_vector_type(4))) float f4_t;    // 4 x f32
typedef __attribute__((ext_vector_type(4))) int   i4_t;    // 16 B LDS write

static __device__ __forceinline__ short f2bf(float f) {
    union { float f; unsigned u; } v; v.f = f;
    unsigned r = v.u + 0x7fffu + ((v.u >> 16) & 1u);   // round-to-nearest-even
    return (short)(r >> 16);
}
static __device__ __forceinline__ float bf2f(short s) {
    union { unsigned u; float f; } v;
    v.u = ((unsigned)(unsigned short)s) << 16;
    return v.f;
}

// ---------------------------------------------------------------------------
// ONE dispatch, zero inter-block sync (r4 structure -- traffic proven ideal:
// FETCH 17.4 MB / WRITE 16.4 MB).  Round-5 fixes the r4 latency structure:
//   * 1024 threads = 16 waves = 4 waves/SIMD (r4 had 2) -- 2x wave hiding.
//   * Each wave owns 16 panel rows over FULL K -> no cross-wave reduction.
//   * P staged in 8 x 128-K chunks, DOUBLE-buffered: next chunk's strided
//     loads issue BEFORE compute (latency hides under MFMA+cvt), LDS write
//     lands AFTER compute into the opposite buffer -> ONE barrier per chunk.
// Phase A math/layout identical to r2/r4 (verified): A-frag = P^T rows from
// swizzled LDS, B-frag = x row slice, D col=nr -> sample, row=quad*4+r -> m.
// Phase B identical to r4 (verified): A=t_j, B=t_i, float4 stores.
// Diagonal blocks: i- and j-panel waves run identical code on identical
// inputs -> bitwise-identical t/norms (deterministic, as in passing r4).
// ---------------------------------------------------------------------------
__global__ void __launch_bounds__(1024, 4)
fused_kernel(const float* __restrict__ x, const float* __restrict__ P,
             float* __restrict__ out)
{
    const int tid  = threadIdx.x;
    const int w    = tid >> 6;          // wave 0..15
    const int lane = tid & 63;
    const int nr   = lane & 15;
    const int quad = lane >> 4;

    // XCD chunk swizzle (bijective, 256 blocks): 32 consecutive tiles/XCD,
    // consecutive tiles share ti -> x i-panel stays hot in that XCD's L2.
    const int swz = (blockIdx.x & 7) * 32 + (blockIdx.x >> 3);
    const int b   = swz >> 6;
    const int ti  = (swz >> 3) & 7;
    const int tj  = swz & 7;

    __shared__ __align__(16) char  p_lds[2][16384];     // P^T chunk [64m][128k] bf16, dbuf
    __shared__ __align__(16) short t_lds[2][128][64];   // bf16 t panels (row-XOR swizzled)
    __shared__ __align__(16) float nrm_lds[2][128];

    // ---------------- phase A: private t panels ----------------
    const int pan  = w >> 3;                 // 0 = i-panel, 1 = j-panel
    const int wl   = w & 7;                  // 8 waves/panel, 16 rows each
    const int srow = wl * 16 + nr;           // panel row 0..127 (per lane)
    const int panbase = (pan ? tj : ti) * 128;
    const float* xr = x + (size_t)(b * 1024 + panbase + srow) * 1024;

    // staging item: thread -> (m, 16B slot); global loads coalesced across m
    const int sm    = tid & 63;              // m 0..63
    const int sks   = tid >> 6;              // slot 0..15 (8 k each)
    const float* psrc = P + (size_t)(sks * 8) * 64 + sm;
    const int pdoff = sm * 256 + ((sks * 16) ^ ((sm & 7) << 4));

    f4_t acc[4];
    #pragma unroll
    for (int mt = 0; mt < 4; mt++) acc[mt] = f4_t{0.f, 0.f, 0.f, 0.f};

    // prologue: stage chunk 0 into buffer 0
    {
        float pr[8];
        #pragma unroll
        for (int j = 0; j < 8; ++j) pr[j] = psrc[j * 64];
        i4_t d;
        d[0] = ((int)(unsigned short)f2bf(pr[1]) << 16) | (unsigned short)f2bf(pr[0]);
        d[1] = ((int)(unsigned short)f2bf(pr[3]) << 16) | (unsigned short)f2bf(pr[2]);
        d[2] = ((int)(unsigned short)f2bf(pr[5]) << 16) | (unsigned short)f2bf(pr[4]);
        d[3] = ((int)(unsigned short)f2bf(pr[7]) << 16) | (unsigned short)f2bf(pr[6]);
        *(i4_t*)(p_lds[0] + pdoff) = d;
    }
    __syncthreads();

    for (int c = 0; c < 8; ++c) {
        // EARLY: next chunk's strided P loads -> regs (latency under compute)
        float prn[8];
        if (c < 7) {
            const float* pn = psrc + (size_t)(c + 1) * (128 * 64);
            #pragma unroll
            for (int j = 0; j < 8; ++j) prn[j] = pn[j * 64];
        }
        // this chunk's x loads (mostly L2-hot thanks to XCD swizzle)
        f4_t xv[4][2];
        #pragma unroll
        for (int kt = 0; kt < 4; ++kt) {
            const float* xp = xr + c * 128 + kt * 32 + quad * 8;
            xv[kt][0] = *(const f4_t*)xp;
            xv[kt][1] = *(const f4_t*)(xp + 4);
        }
        // compute chunk c from buffer c&1
        const char* pb = p_lds[c & 1];
        #pragma unroll
        for (int kt = 0; kt < 4; ++kt) {
            const int colb = (kt * 64 + quad * 16) ^ ((nr & 7) << 4);
            bf8_t afr0 = *(const bf8_t*)(pb + (0 * 16 + nr) * 256 + colb);
            bf8_t afr1 = *(const bf8_t*)(pb + (1 * 16 + nr) * 256 + colb);
            bf8_t afr2 = *(const bf8_t*)(pb + (2 * 16 + nr) * 256 + colb);
            bf8_t afr3 = *(const bf8_t*)(pb + (3 * 16 + nr) * 256 + colb);
            bf8_t bfr;
            #pragma unroll
            for (int j = 0; j < 4; ++j) {
                bfr[j]     = f2bf(xv[kt][0][j]);
                bfr[4 + j] = f2bf(xv[kt][1][j]);
            }
            acc[0] = __builtin_amdgcn_mfma_f32_16x16x32_bf16(afr0, bfr, acc[0], 0, 0, 0);
            acc[1] = __builtin_amdgcn_mfma_f32_16x16x32_bf16(afr1, bfr, acc[1], 0, 0, 0);
            acc[2] = __builtin_amdgcn_mfma_f32_16x16x32_bf16(afr2, bfr, acc[2], 0, 0, 0);
            acc[3] = __builtin_amdgcn_mfma_f32_16x16x32_bf16(afr3, bfr, acc[3], 0, 0, 0);
        }
        // LATE: write next chunk into the OTHER buffer (safe pre-barrier:
        // its previous readers finished before the barrier that ended c-1)
        if (c < 7) {
            i4_t d;
            d[0] = ((int)(unsigned short)f2bf(prn[1]) << 16) | (unsigned short)f2bf(prn[0]);
            d[1] = ((int)(unsigned short)f2bf(prn[3]) << 16) | (unsigned short)f2bf(prn[2]);
            d[2] = ((int)(unsigned short)f2bf(prn[5]) << 16) | (unsigned short)f2bf(prn[4]);
            d[3] = ((int)(unsigned short)f2bf(prn[7]) << 16) | (unsigned short)f2bf(prn[6]);
            *(i4_t*)(p_lds[(c + 1) & 1] + pdoff) = d;
        }
        __syncthreads();   // one barrier per chunk, 4 waves/SIMD of slack
    }

    // epilogue: round to bf16, write t_lds (swizzled) + norms from ROUNDED
    {
        char* trow = (char*)t_lds[pan] + srow * 128;
        float nrm = 0.f;
        #pragma unroll
        for (int mt = 0; mt < 4; ++mt) {
            const short s0 = f2bf(acc[mt][0]), s1 = f2bf(acc[mt][1]);
            const short s2 = f2bf(acc[mt][2]), s3 = f2bf(acc[mt][3]);
            const float b0 = bf2f(s0), b1 = bf2f(s1), b2 = bf2f(s2), b3 = bf2f(s3);
            nrm += b0 * b0 + b1 * b1 + b2 * b2 + b3 * b3;
            uint2 pk;
            pk.x = ((unsigned)(unsigned short)s1 << 16) | (unsigned short)s0;
            pk.y = ((unsigned)(unsigned short)s3 << 16) | (unsigned short)s2;
            // m = mt*16 + quad*4 + {0..3} -> byte mt*32 + quad*8, row-swizzled
            *(uint2*)(trow + ((mt * 32 + quad * 8) ^ ((srow & 7) << 4))) = pk;
        }
        nrm += __shfl_xor(nrm, 16);
        nrm += __shfl_xor(nrm, 32);
        if (quad == 0) nrm_lds[pan][srow] = nrm;
    }
    __syncthreads();

    // ---------------- phase B: pairwise 128x128 from LDS ----------------
    const int wy = w >> 2;                   // i block of 32 (0..3)
    const int wx = w & 3;                    // j block of 32 (0..3)
    const int i0 = wy * 32, j0 = wx * 32;

    f4_t pac[2][2];
    #pragma unroll
    for (int ia = 0; ia < 2; ia++)
        #pragma unroll
        for (int jb = 0; jb < 2; jb++) pac[ia][jb] = f4_t{0.f, 0.f, 0.f, 0.f};

    #pragma unroll
    for (int kt = 0; kt < 2; ++kt) {
        const int colb = kt * 64 + quad * 16;
        bf8_t A[2], Bv[2];
        #pragma unroll
        for (int jb = 0; jb < 2; ++jb) {
            const int row = j0 + jb * 16 + nr;
            A[jb] = *(const bf8_t*)((char*)t_lds[1] + row * 128 + (colb ^ ((row & 7) << 4)));
        }
        #pragma unroll
        for (int ia = 0; ia < 2; ++ia) {
            const int row = i0 + ia * 16 + nr;
            Bv[ia] = *(const bf8_t*)((char*)t_lds[0] + row * 128 + (colb ^ ((row & 7) << 4)));
        }
        #pragma unroll
        for (int ia = 0; ia < 2; ++ia)
            #pragma unroll
            for (int jb = 0; jb < 2; ++jb)
                pac[ia][jb] = __builtin_amdgcn_mfma_f32_16x16x32_bf16(A[jb], Bv[ia], pac[ia][jb], 0, 0, 0);
    }

    // out = n_i + n_j - 2*G ; D col = nr -> i, row = quad*4+r -> j (float4)
    #pragma unroll
    for (int ia = 0; ia < 2; ++ia) {
        const int il  = i0 + ia * 16 + nr;
        const float niv = nrm_lds[0][il];
        float* orow = out + ((size_t)(b * 1024 + ti * 128 + il)) * 1024 + tj * 128;
        #pragma unroll
        for (int jb = 0; jb < 2; ++jb) {
            const int jo = j0 + jb * 16 + quad * 4;
            const float4 nv = *(const float4*)&nrm_lds[1][jo];   // 16B aligned
            f4_t a = pac[ia][jb];
            float4 v;
            v.x = niv + nv.x - 2.f * a[0];
            v.y = niv + nv.y - 2.f * a[1];
            v.z = niv + nv.z - 2.f * a[2];
            v.w = niv + nv.w - 2.f * a[3];
            *(float4*)(orow + jo) = v;
        }
    }
}

// ---------------------------------------------------------------------------
extern "C" void kernel_launch(void* const* d_in, const int* in_sizes, int n_in,
                              void* d_out, int out_size, void* d_ws, size_t ws_size,
                              hipStream_t stream) {
    const float* x = (const float*)d_in[0];   // [4,1024,1024] fp32
    const float* P = (const float*)d_in[1];   // [1024,64]     fp32
    float* out = (float*)d_out;               // [4,1024,1024] fp32
    (void)d_ws; (void)ws_size;                // no workspace, no memset, 1 dispatch

    fused_kernel<<<256, 1024, 0, stream>>>(x, P, out);
}

// Round 6
// 81.564 us; speedup vs baseline: 1.3437x; 1.3163x over previous
//
#include <hip/hip_runtime.h>

typedef __attribute__((ext_vector_type(8))) short bf8_t;   // 8 x bf16 (4 VGPRs)
typedef __attribute__((ext_vector_type(4))) float f4_t;    // 4 x f32 acc

static __device__ __forceinline__ short f2bf(float f) {
    union { float f; unsigned u; } v; v.f = f;
    unsigned r = v.u + 0x7fffu + ((v.u >> 16) & 1u);   // round-to-nearest-even
    return (short)(r >> 16);
}
static __device__ __forceinline__ float bf2f(short s) {
    union { unsigned u; float f; } v;
    v.u = ((unsigned)(unsigned short)s) << 16;
    return v.f;
}

// ---------------------------------------------------------------------------
// K0: P [1024 k][64 n] fp32  ->  Pt [64 n][1024 k] bf16   (r0-exact, verified)
// ---------------------------------------------------------------------------
__global__ void __launch_bounds__(256)
transpose_p(const float* __restrict__ P, short* __restrict__ Pt) {
    int idx = blockIdx.x * 256 + threadIdx.x;   // 0..65535
    int n = idx >> 10, k = idx & 1023;
    Pt[idx] = f2bf(P[k * 64 + n]);
}

// ---------------------------------------------------------------------------
// K1: t = x @ P as D = P^T (A) x x^T (B).  r0-exact (verified, part of the
// best 79.8us config).  One block per 16-sample tile; 4 waves K-split 256
// each, LDS reduce.  Wave 0 rounds t to bf16, stores [4096][64] + fp32 row
// norms computed FROM the rounded bf16 (diagonal consistency with K2).
// ---------------------------------------------------------------------------
__global__ void __launch_bounds__(256)
proj_kernel(const float* __restrict__ x, const short* __restrict__ Pt,
            short* __restrict__ t, float* __restrict__ norms) {
    const int w    = threadIdx.x >> 6;     // wave id 0..3 (K-split)
    const int lane = threadIdx.x & 63;
    const int nr   = lane & 15;            // sample within tile / rank m-lane
    const int quad = lane >> 4;
    const int row  = blockIdx.x * 16 + nr; // global sample row

    f4_t acc[4];
    #pragma unroll
    for (int mt = 0; mt < 4; mt++) acc[mt] = f4_t{0.f, 0.f, 0.f, 0.f};

    const float* xr = x + (size_t)row * 1024;
    #pragma unroll
    for (int kt = 0; kt < 8; kt++) {
        const int kb = w * 256 + kt * 32 + quad * 8;
        f4_t x0 = *(const f4_t*)(xr + kb);
        f4_t x1 = *(const f4_t*)(xr + kb + 4);
        bf8_t bfr;
        bfr[0] = f2bf(x0[0]); bfr[1] = f2bf(x0[1]);
        bfr[2] = f2bf(x0[2]); bfr[3] = f2bf(x0[3]);
        bfr[4] = f2bf(x1[0]); bfr[5] = f2bf(x1[1]);
        bfr[6] = f2bf(x1[2]); bfr[7] = f2bf(x1[3]);
        #pragma unroll
        for (int mt = 0; mt < 4; mt++) {
            bf8_t afr = *(const bf8_t*)(Pt + (size_t)(mt * 16 + nr) * 1024 + kb);
            acc[mt] = __builtin_amdgcn_mfma_f32_16x16x32_bf16(afr, bfr, acc[mt], 0, 0, 0);
        }
    }

    // cross-wave (K-split) reduction through LDS
    __shared__ float red[3][16][64];
    if (w > 0) {
        #pragma unroll
        for (int mt = 0; mt < 4; mt++)
            #pragma unroll
            for (int r = 0; r < 4; r++)
                red[w - 1][mt * 4 + r][lane] = acc[mt][r];
    }
    __syncthreads();

    if (w == 0) {
        float nrm = 0.f;
        #pragma unroll
        for (int mt = 0; mt < 4; mt++) {
            float v0 = acc[mt][0] + red[0][mt*4+0][lane] + red[1][mt*4+0][lane] + red[2][mt*4+0][lane];
            float v1 = acc[mt][1] + red[0][mt*4+1][lane] + red[1][mt*4+1][lane] + red[2][mt*4+1][lane];
            float v2 = acc[mt][2] + red[0][mt*4+2][lane] + red[1][mt*4+2][lane] + red[2][mt*4+2][lane];
            float v3 = acc[mt][3] + red[0][mt*4+3][lane] + red[1][mt*4+3][lane] + red[2][mt*4+3][lane];
            short s0 = f2bf(v0), s1 = f2bf(v1), s2 = f2bf(v2), s3 = f2bf(v3);
            float b0 = bf2f(s0), b1 = bf2f(s1), b2 = bf2f(s2), b3 = bf2f(s3);
            nrm += b0*b0 + b1*b1 + b2*b2 + b3*b3;
            short4 sv; sv.x = s0; sv.y = s1; sv.z = s2; sv.w = s3;
            // lane holds t[row][m] for m = mt*16 + quad*4 + {0..3}
            *(short4*)(t + (size_t)row * 64 + mt * 16 + quad * 4) = sv;
        }
        nrm += __shfl_xor(nrm, 16);
        nrm += __shfl_xor(nrm, 32);
        if (quad == 0) norms[row] = nrm;
    }
}

// ---------------------------------------------------------------------------
// K2: out[b,i,j] = n_i + n_j - 2*dot(t_i,t_j).  r3-exact (verified).
// 64x64 tiles -> 1024 blocks (4/CU co-resident, 4x the latency hiding of the
// r0 version), 4 waves (2x2) of 32x32.  MFMA operands swapped (A = t_j frag,
// B = t_i frag) so the D register quad holds 4 consecutive j -> float4
// epilogue stores (4/lane vs r0's 64 scalar dwords).  Chunked XCD swizzle
// keeps blocks sharing an i-panel on one XCD's L2 (t = 512 KB, L2-resident).
// ---------------------------------------------------------------------------
__global__ void __launch_bounds__(256, 4)
pairwise_kernel(const short* __restrict__ t, const float* __restrict__ norms,
                float* __restrict__ out)
{
    const int b    = blockIdx.y;
    // bijective chunked XCD swizzle over 256 x-blocks: 32 consecutive per XCD
    const int swz  = (blockIdx.x & 7) * 32 + (blockIdx.x >> 3);
    const int ti   = swz >> 4;           // 0..15 (64-row i panel)
    const int tj   = swz & 15;           // 0..15 (64-col j panel)
    const int tid  = threadIdx.x;
    const int w    = tid >> 6;
    const int lane = tid & 63;
    const int wy   = w >> 1, wx = w & 1;
    const int i0   = ti * 64 + wy * 32;
    const int j0   = tj * 64 + wx * 32;
    const int nr   = lane & 15, quad = lane >> 4;

    __shared__ float ni[64], nj[64];
    if (tid < 64)       ni[tid]      = norms[b * 1024 + ti * 64 + tid];
    else if (tid < 128) nj[tid - 64] = norms[b * 1024 + tj * 64 + (tid - 64)];
    __syncthreads();

    const short* tb = t + (size_t)b * 1024 * 64;

    f4_t acc[2][2];
    #pragma unroll
    for (int ia = 0; ia < 2; ia++)
        #pragma unroll
        for (int jb = 0; jb < 2; jb++) acc[ia][jb] = f4_t{0.f, 0.f, 0.f, 0.f};

    #pragma unroll
    for (int kt = 0; kt < 2; kt++) {
        const int kb = kt * 32 + quad * 8;
        bf8_t A[2], B[2];
        #pragma unroll
        for (int jb = 0; jb < 2; jb++)     // A operand <- j rows
            A[jb] = *(const bf8_t*)(tb + (size_t)(j0 + jb * 16 + nr) * 64 + kb);
        #pragma unroll
        for (int ia = 0; ia < 2; ia++)     // B operand <- i rows
            B[ia] = *(const bf8_t*)(tb + (size_t)(i0 + ia * 16 + nr) * 64 + kb);
        #pragma unroll
        for (int ia = 0; ia < 2; ia++)
            #pragma unroll
            for (int jb = 0; jb < 2; jb++)
                acc[ia][jb] = __builtin_amdgcn_mfma_f32_16x16x32_bf16(A[jb], B[ia], acc[ia][jb], 0, 0, 0);
    }

    // D layout (verified): col = nr -> i, row = quad*4 + r -> j (float4)
    #pragma unroll
    for (int ia = 0; ia < 2; ia++) {
        const int i = i0 + ia * 16 + nr;
        const float niv = ni[wy * 32 + ia * 16 + nr];
        float* orow = out + ((size_t)b * 1024 + i) * 1024 + tj * 64;
        #pragma unroll
        for (int jb = 0; jb < 2; jb++) {
            const int jo = wx * 32 + jb * 16 + quad * 4;
            const float4 nv = *(const float4*)&nj[jo];   // broadcast, conflict-free
            f4_t a = acc[ia][jb];
            float4 v;
            v.x = niv + nv.x - 2.f * a[0];
            v.y = niv + nv.y - 2.f * a[1];
            v.z = niv + nv.z - 2.f * a[2];
            v.w = niv + nv.w - 2.f * a[3];
            *(float4*)(orow + jo) = v;                   // 16 B/lane
        }
    }
}

// ---------------------------------------------------------------------------
extern "C" void kernel_launch(void* const* d_in, const int* in_sizes, int n_in,
                              void* d_out, int out_size, void* d_ws, size_t ws_size,
                              hipStream_t stream) {
    const float* x = (const float*)d_in[0];   // [4,1024,1024] fp32
    const float* P = (const float*)d_in[1];   // [1024,64]     fp32
    float* out = (float*)d_out;               // [4,1024,1024] fp32

    // workspace layout: Pt (128 KB bf16) | t (512 KB bf16) | norms (16 KB f32)
    short* Pt    = (short*)d_ws;
    short* t     = (short*)d_ws + 65536;
    float* norms = (float*)((char*)d_ws + (128 + 512) * 1024);

    transpose_p<<<256, 256, 0, stream>>>(P, Pt);
    proj_kernel<<<256, 256, 0, stream>>>(x, Pt, t, norms);
    dim3 g2(256, 4);
    pairwise_kernel<<<g2, 256, 0, stream>>>(t, norms, out);
}